// Round 6
// baseline (1726.622 us; speedup 1.0000x reference)
//
#include <hip/hip_runtime.h>
#include <hip/hip_bf16.h>
#include <stdint.h>

typedef __bf16 bf16_t;
typedef __bf16 bf16x8 __attribute__((ext_vector_type(8)));
typedef float f32x4 __attribute__((ext_vector_type(4)));

#define AS1(p) ((const __attribute__((address_space(1))) void*)(uintptr_t)(p))
#define AS3(p) ((__attribute__((address_space(3))) void*)(uintptr_t)(p))

__device__ __forceinline__ void gload16(const bf16_t* g, bf16_t* l) {
  __builtin_amdgcn_global_load_lds(AS1(g), AS3(l), 16, 0, 0);
}

#define SBAR()   __builtin_amdgcn_sched_barrier(0);
#define BAR()    { __builtin_amdgcn_sched_barrier(0); __builtin_amdgcn_s_barrier(); __builtin_amdgcn_sched_barrier(0); }
#define VMCNT0() { asm volatile("s_waitcnt vmcnt(0)" ::: "memory"); __builtin_amdgcn_sched_barrier(0); }
#define LGKM0()  { asm volatile("s_waitcnt lgkmcnt(0)" ::: "memory"); __builtin_amdgcn_sched_barrier(0); }

// ========== 256x256 GEMM core (B^T form), quadrant-phase schedule ==========
// C[m][n] = sum_k A[m][k]*B[n][k]. 512 threads = 8 waves (2M x 4N), per-wave 128x64.
// BK=64 as 2 k-halves; LDS buf: A kh0|A kh1|B kh0|B kh1 (16KB each); 2 bufs = 128 KiB.
// Half layout [256 rows][32 k] bf16, XOR swizzle byte^=((byte>>7)&7)<<4 (write side:
// linear LDS dest + pre-swizzled global source; read side same XOR) -> conflict-free.
// Sync skeleton (race-free, R3-proven): full next-tile stage issued at tile top,
// ONE vmcnt(0)+barrier per tile (R5 showed counted vmcnt == drain here).
// NEW (m201 discipline): compute split into 4 quadrant phases per tile:
//   {reads (12 or 4 ds_read_b128) -> BAR -> lgkm0 -> 16 MFMA (setprio) -> BAR}
// so phase q+1's reads are serviced by the LDS unit while phase q's MFMAs drain.
__device__ __forceinline__ void gemm256(const bf16_t* __restrict__ A, int lda,
                                        const bf16_t* __restrict__ B, int ldb,
                                        int nt, f32x4 acc[8][4], bf16_t* lds) {
  const int t = (int)threadIdx.x;
  const int lane = t & 63, w = t >> 6;
  const int wr = w >> 2, wc = w & 3;
  const int fr = lane & 15, fq = lane >> 4;
  char* ldsb = (char*)lds;

  // staging: thread t writes LDS bytes [t*16,+16) of each 8KB chunk (linear);
  // global source pre-swizzled so the swizzled read sees the right data
  const int s0 = (t * 16) ^ (((t >> 3) & 7) << 4);
  const int r0 = s0 >> 6, q0 = (s0 >> 4) & 3;
  const bf16_t* gA0 = A + (size_t)r0 * lda + q0 * 8;
  const bf16_t* gA1 = gA0 + (size_t)128 * lda;
  const bf16_t* gB0 = B + (size_t)r0 * ldb + q0 * 8;
  const bf16_t* gB1 = gB0 + (size_t)128 * ldb;

  // frag read bases (bytes). bits[9:7] of in-half offset = fr>>1 for all frags.
  const int swz = (fr * 64 + fq * 16) ^ (((fr >> 1) & 7) << 4);
  const int abase = wr * 8192 + swz;   // A: rows wr*128..+128 of the half
  const int bbase = wc * 4096 + swz;   // B: rows wc*64..+64 of the half

  bf16x8 bb0[4], bb1[4];
  bf16x8 pA0, pA1, pA2, pA3;  // quadrant set A (kk0: mi pair, kk1: mi pair)
  bf16x8 pB0, pB1, pB2, pB3;  // quadrant set B

#define STAGE(cb, kof) { \
    bf16_t* _d = lds + (cb) * 32768; \
    gload16(gA0 + (kof),      _d + t * 8); \
    gload16(gA1 + (kof),      _d + 4096 + t * 8); \
    gload16(gA0 + (kof) + 32, _d + 8192 + t * 8); \
    gload16(gA1 + (kof) + 32, _d + 12288 + t * 8); \
    gload16(gB0 + (kof),      _d + 16384 + t * 8); \
    gload16(gB1 + (kof),      _d + 20480 + t * 8); \
    gload16(gB0 + (kof) + 32, _d + 24576 + t * 8); \
    gload16(gB1 + (kof) + 32, _d + 28672 + t * 8); \
  } SBAR()
#define DS_B2(cb) { \
    const char* _b = ldsb + (cb) * 65536 + 32768 + bbase; \
    _Pragma("unroll") for (int n = 0; n < 4; ++n) bb0[n] = *(const bf16x8*)(_b + n * 1024); \
    _Pragma("unroll") for (int n = 0; n < 4; ++n) bb1[n] = *(const bf16x8*)(_b + 16384 + n * 1024); }
#define DS_AQ(cb, q, d0, d1, d2, d3) { \
    const char* _a = ldsb + (cb) * 65536 + abase + (q) * 2048; \
    d0 = *(const bf16x8*)(_a); \
    d1 = *(const bf16x8*)(_a + 1024); \
    d2 = *(const bf16x8*)(_a + 16384); \
    d3 = *(const bf16x8*)(_a + 16384 + 1024); }
#define MFMA16(q, d0, d1, d2, d3) { \
    __builtin_amdgcn_s_setprio(1); \
    _Pragma("unroll") for (int n = 0; n < 4; ++n) \
      acc[2 * (q)][n]     = __builtin_amdgcn_mfma_f32_16x16x32_bf16(d0, bb0[n], acc[2 * (q)][n], 0, 0, 0); \
    _Pragma("unroll") for (int n = 0; n < 4; ++n) \
      acc[2 * (q) + 1][n] = __builtin_amdgcn_mfma_f32_16x16x32_bf16(d1, bb0[n], acc[2 * (q) + 1][n], 0, 0, 0); \
    _Pragma("unroll") for (int n = 0; n < 4; ++n) \
      acc[2 * (q)][n]     = __builtin_amdgcn_mfma_f32_16x16x32_bf16(d2, bb1[n], acc[2 * (q)][n], 0, 0, 0); \
    _Pragma("unroll") for (int n = 0; n < 4; ++n) \
      acc[2 * (q) + 1][n] = __builtin_amdgcn_mfma_f32_16x16x32_bf16(d3, bb1[n], acc[2 * (q) + 1][n], 0, 0, 0); \
    __builtin_amdgcn_s_setprio(0); }

  // prologue: stage tile 0 into buf0, drain, barrier
  STAGE(0, 0)
  VMCNT0() BAR()

  int kof = 64;
  for (int tt = 0; tt < nt - 1; ++tt, kof += 64) {
    const int cb = tt & 1;
    STAGE(cb ^ 1, kof)                                     // full next-tile prefetch
    DS_B2(cb) DS_AQ(cb, 0, pA0, pA1, pA2, pA3)             // phase 0 reads (12)
    BAR() LGKM0() MFMA16(0, pA0, pA1, pA2, pA3) BAR()
    DS_AQ(cb, 1, pB0, pB1, pB2, pB3)                       // phase 1 reads (4)
    BAR() LGKM0() MFMA16(1, pB0, pB1, pB2, pB3) BAR()
    DS_AQ(cb, 2, pA0, pA1, pA2, pA3)
    BAR() LGKM0() MFMA16(2, pA0, pA1, pA2, pA3) BAR()
    DS_AQ(cb, 3, pB0, pB1, pB2, pB3)
    BAR() LGKM0() MFMA16(3, pB0, pB1, pB2, pB3)
    VMCNT0() BAR()                                         // tile-end drain (race-free)
  }
  {  // tail tile: reads only
    const int cb = (nt - 1) & 1;
    DS_B2(cb) DS_AQ(cb, 0, pA0, pA1, pA2, pA3)
    BAR() LGKM0() MFMA16(0, pA0, pA1, pA2, pA3) BAR()
    DS_AQ(cb, 1, pB0, pB1, pB2, pB3)
    BAR() LGKM0() MFMA16(1, pB0, pB1, pB2, pB3) BAR()
    DS_AQ(cb, 2, pA0, pA1, pA2, pA3)
    BAR() LGKM0() MFMA16(2, pA0, pA1, pA2, pA3) BAR()
    DS_AQ(cb, 3, pB0, pB1, pB2, pB3)
    BAR() LGKM0() MFMA16(3, pB0, pB1, pB2, pB3)
  }
#undef STAGE
#undef DS_B2
#undef DS_AQ
#undef MFMA16
}

#define EPI_VARS \
  const int t = (int)threadIdx.x; \
  const int lane = t & 63, w = t >> 6; \
  const int wr = w >> 2, wc = w & 3; \
  const int fr = lane & 15, fq = lane >> 4;

#define ZERO8x4(acc) \
  _Pragma("unroll") for (int _i = 0; _i < 8; ++_i) \
  _Pragma("unroll") for (int _j = 0; _j < 4; ++_j) { f32x4 _z = {0.f,0.f,0.f,0.f}; acc[_i][_j] = _z; }

// ---------------- conversions ----------------
__global__ void k_cvt(const float* __restrict__ s, bf16_t* __restrict__ d, long n8) {
  long i = (long)blockIdx.x * blockDim.x + threadIdx.x;
  long st = (long)gridDim.x * blockDim.x;
  for (; i < n8; i += st) {
    const float4* sp = (const float4*)(s + i * 8);
    float4 a = sp[0], b = sp[1];
    bf16x8 v;
    v[0] = (__bf16)a.x; v[1] = (__bf16)a.y; v[2] = (__bf16)a.z; v[3] = (__bf16)a.w;
    v[4] = (__bf16)b.x; v[5] = (__bf16)b.y; v[6] = (__bf16)b.z; v[7] = (__bf16)b.w;
    *(bf16x8*)(d + i * 8) = v;
  }
}

__global__ void k_fill(float* o, float v, long n) {
  long i = (long)blockIdx.x * blockDim.x + threadIdx.x;
  long st = (long)gridDim.x * blockDim.x;
  for (; i < n; i += st) o[i] = v;
}

// ---------------- GEMM 1: QKV projection (256-tile) ----------------
__global__ __launch_bounds__(512, 2) void k_qkv256(
    const bf16_t* __restrict__ xb, const bf16_t* __restrict__ Wb,
    const float* __restrict__ bq, const float* __restrict__ bk, const float* __restrict__ bv,
    bf16_t* __restrict__ Q, bf16_t* __restrict__ K, bf16_t* __restrict__ Vt) {
  __shared__ __align__(16) bf16_t lds[65536];
  int bid = (int)blockIdx.x;
  int id = (bid & 7) * 384 + (bid >> 3);  // XCD-bijective swizzle (3072 = 8*384)
  EPI_VARS
  f32x4 acc[8][4];
  ZERO8x4(acc)

  bool vmode = id >= 2048;
  int mt = 0, ntile = 0, tok = 0, wm = 0;
  const bf16_t *Ap, *Bp;
  if (!vmode) {
    mt = id & 127; ntile = id >> 7;  // B-panel-major: resident blocks share W panel
    Ap = xb + (size_t)mt * 256 * 2048;
    Bp = Wb + (size_t)ntile * 256 * 2048;
  } else {
    int vb = id - 2048;
    tok = vb & 127; wm = vb >> 7;
    Ap = Wb + (size_t)(16 + wm) * 256 * 2048;
    Bp = xb + (size_t)tok * 256 * 2048;
  }
  gemm256(Ap, 2048, Bp, 2048, 32, acc, lds);

  if (!vmode) {
    int sel = ntile >> 3;  // 0 -> Q, 1 -> K
    const float* bias = sel ? bk : bq;
    bf16_t* dst = sel ? K : Q;
    int cbase = (ntile & 7) * 256 + wc * 64;
#pragma unroll
    for (int ni = 0; ni < 4; ++ni) {
      int c2 = cbase + ni * 16 + fr;  // [0,2048)
      int h = c2 >> 10, d = c2 & 1023;
      float bb = bias[c2];
#pragma unroll
      for (int mi = 0; mi < 8; ++mi) {
        f32x4 a = acc[mi][ni];
#pragma unroll
        for (int r = 0; r < 4; ++r) {
          int m = mt * 256 + wr * 128 + mi * 16 + fq * 4 + r;
          int b = m >> 10, tk = m & 1023;
          dst[(((size_t)(b * 2 + h) << 10) + tk) * 1024 + d] = (bf16_t)(a[r] + bb);
        }
      }
    }
  } else {
#pragma unroll
    for (int mi = 0; mi < 8; ++mi) {
#pragma unroll
      for (int r = 0; r < 4; ++r) {
        int gd = wm * 256 + wr * 128 + mi * 16 + fq * 4 + r;  // [0,2048)
        int h = gd >> 10, d = gd & 1023;
        float bb = bv[gd];
#pragma unroll
        for (int ni = 0; ni < 4; ++ni) {
          int m = tok * 256 + wc * 64 + ni * 16 + fr;
          int b = m >> 10, tk = m & 1023;
          Vt[(((size_t)(b * 2 + h) << 10) + d) * 1024 + tk] = (bf16_t)(acc[mi][ni][r] + bb);
        }
      }
    }
  }
}

// ---------------- GEMM 2: S = Q K^T * scale (lower-tri 256-tiles) ----------------
__global__ __launch_bounds__(512, 2) void k_s256(const bf16_t* __restrict__ Q,
                                                 const bf16_t* __restrict__ K,
                                                 float* __restrict__ S, int pbase) {
  __shared__ __align__(16) bf16_t lds[65536];
  int id = (int)blockIdx.x;
  int pc = id / 10, rem = id % 10;
  int ti = 0;
  while (rem > ti) { rem -= ti + 1; ++ti; }
  int tj = rem;
  size_t p = (size_t)(pbase + pc);
  EPI_VARS
  f32x4 acc[8][4];
  ZERO8x4(acc)
  gemm256(Q + (p << 20) + (size_t)ti * 256 * 1024, 1024,
          K + (p << 20) + (size_t)tj * 256 * 1024, 1024, 16, acc, lds);
  float* Sp = S + ((size_t)pc << 20);
  const float scale = 0.022097086912079608f;  // 1/sqrt(2048)
#pragma unroll
  for (int mi = 0; mi < 8; ++mi)
#pragma unroll
    for (int ni = 0; ni < 4; ++ni) {
      int col = tj * 256 + wc * 64 + ni * 16 + fr;
      f32x4 a = acc[mi][ni];
#pragma unroll
      for (int r = 0; r < 4; ++r) {
        int row = ti * 256 + wr * 128 + mi * 16 + fq * 4 + r;
        Sp[((size_t)row << 10) + col] = a[r] * scale;
      }
    }
}

// ---------------- softmax (one block per row, causal); zero-fills to 256-aligned end
__global__ __launch_bounds__(256) void k_softmax(const float* __restrict__ S,
                                                 bf16_t* __restrict__ P) {
  int bid = blockIdx.x;
  int pc = bid >> 10, row = bid & 1023;
  const float* s = S + ((size_t)pc << 20) + ((size_t)row << 10);
  bf16_t* p = P + ((size_t)pc << 20) + ((size_t)row << 10);
  int cend = ((row >> 8) + 1) << 8;  // 256-aligned (PV K-tile width)
  int t = threadIdx.x;
  __shared__ float red[8];
  float x[4];
  float mx = -1e30f;
#pragma unroll
  for (int j = 0; j < 4; ++j) {
    int c = t + 256 * j;
    x[j] = (c <= row) ? s[c] : -1e30f;
    mx = fmaxf(mx, x[j]);
  }
  for (int o = 32; o > 0; o >>= 1) mx = fmaxf(mx, __shfl_xor(mx, o));
  if (!(t & 63)) red[t >> 6] = mx;
  __syncthreads();
  mx = fmaxf(fmaxf(red[0], red[1]), fmaxf(red[2], red[3]));
  float e[4];
  float sum = 0.f;
#pragma unroll
  for (int j = 0; j < 4; ++j) {
    e[j] = (x[j] > -1e29f) ? __expf(x[j] - mx) : 0.f;
    sum += e[j];
  }
  for (int o = 32; o > 0; o >>= 1) sum += __shfl_xor(sum, o);
  if (!(t & 63)) red[4 + (t >> 6)] = sum;
  __syncthreads();
  sum = red[4] + red[5] + red[6] + red[7];
  float inv = 1.f / sum;
#pragma unroll
  for (int j = 0; j < 4; ++j) {
    int c = t + 256 * j;
    if (c < cend) p[c] = (bf16_t)(e[j] * inv);
  }
}

// ---------------- GEMM 3: O = P * V (V pre-transposed; causal-shortened K) ----------------
__global__ __launch_bounds__(512, 2) void k_pv256(const bf16_t* __restrict__ P,
                                                  const bf16_t* __restrict__ Vt,
                                                  bf16_t* __restrict__ O, int pbase) {
  __shared__ __align__(16) bf16_t lds[65536];
  int id = (int)blockIdx.x;
  int pc = id >> 4, rem = id & 15;
  int ti = rem >> 2, dj = rem & 3;
  size_t p = (size_t)(pbase + pc);
  EPI_VARS
  f32x4 acc[8][4];
  ZERO8x4(acc)
  gemm256(P + ((size_t)pc << 20) + (size_t)ti * 256 * 1024, 1024,
          Vt + (p << 20) + (size_t)dj * 256 * 1024, 1024, (ti + 1) * 4, acc, lds);
  int b = (int)(p >> 1), h = (int)(p & 1);
#pragma unroll
  for (int mi = 0; mi < 8; ++mi)
#pragma unroll
    for (int ni = 0; ni < 4; ++ni) {
      int dcol = dj * 256 + wc * 64 + ni * 16 + fr;
      f32x4 a = acc[mi][ni];
#pragma unroll
      for (int r = 0; r < 4; ++r) {
        int tk = ti * 256 + wr * 128 + mi * 16 + fq * 4 + r;
        O[(((size_t)b << 10) + tk) * 2048 + (h << 10) + dcol] = (bf16_t)a[r];
      }
    }
}

// ---------------- GEMM 4: out = O * Wo^T (fp32 out) ----------------
__global__ __launch_bounds__(512, 2) void k_out256(const bf16_t* __restrict__ O,
                                                   const bf16_t* __restrict__ W,
                                                   float* __restrict__ out) {
  __shared__ __align__(16) bf16_t lds[65536];
  int bid = (int)blockIdx.x;
  int id = (bid & 7) * 128 + (bid >> 3);  // XCD swizzle (1024 = 8*128)
  int mt = id & 127, ntile = id >> 7;     // B-panel-major
  EPI_VARS
  f32x4 acc[8][4];
  ZERO8x4(acc)
  gemm256(O + (size_t)mt * 256 * 2048, 2048, W + (size_t)ntile * 256 * 2048, 2048, 32, acc, lds);
#pragma unroll
  for (int mi = 0; mi < 8; ++mi)
#pragma unroll
    for (int ni = 0; ni < 4; ++ni) {
      int col = ntile * 256 + wc * 64 + ni * 16 + fr;
      f32x4 a = acc[mi][ni];
#pragma unroll
      for (int r = 0; r < 4; ++r) {
        int row = mt * 256 + wr * 128 + mi * 16 + fq * 4 + r;
        out[(size_t)row * 2048 + col] = a[r];
      }
    }
}

// ---------------- launch ----------------
extern "C" void kernel_launch(void* const* d_in, const int* in_sizes, int n_in,
                              void* d_out, int out_size, void* d_ws, size_t ws_size,
                              hipStream_t stream) {
  const float* x  = (const float*)d_in[0];
  const float* Wq = (const float*)d_in[1];
  const float* bq = (const float*)d_in[2];
  const float* Wk = (const float*)d_in[3];
  const float* bk = (const float*)d_in[4];
  const float* Wv = (const float*)d_in[5];
  const float* bv = (const float*)d_in[6];
  const float* Wo = (const float*)d_in[7];
  float* out = (float*)d_out;

  const size_t MiB = 1ull << 20;
  char* w = (char*)d_ws;
  bf16_t* xb    = (bf16_t*)w;               // 128 MiB, reused as O after QKV
  bf16_t* Ob    = xb;
  bf16_t* Qb    = (bf16_t*)(w + 128 * MiB); // 128 MiB
  bf16_t* Kb    = (bf16_t*)(w + 256 * MiB); // 128 MiB
  bf16_t* Vt    = (bf16_t*)(w + 384 * MiB); // 128 MiB (transposed V)
  bf16_t* Wqkvb = (bf16_t*)(w + 512 * MiB); // 24 MiB  [Wq;Wk;Wv]
  bf16_t* Wob   = (bf16_t*)(w + 536 * MiB); // 8 MiB
  float*  Sc    = (float*)(w + 544 * MiB);  // NP * 4 MiB

  size_t rem = ws_size > 544 * MiB ? ws_size - 544 * MiB : 0;
  int NP = (int)(rem / (6 * MiB));
  if (NP > 64) NP = 64;
  if (NP < 1) {
    k_fill<<<2048, 256, 0, stream>>>(out, (float)(ws_size >> 20), (long)out_size);
    return;
  }
  bf16_t* Pc = (bf16_t*)(w + 544 * MiB + (size_t)NP * 4 * MiB); // NP * 2 MiB

  // conversions to bf16
  k_cvt<<<2048, 256, 0, stream>>>(x, xb, 8388608L);
  k_cvt<<<1024, 256, 0, stream>>>(Wq, Wqkvb, 524288L);
  k_cvt<<<1024, 256, 0, stream>>>(Wk, Wqkvb + 4194304, 524288L);
  k_cvt<<<1024, 256, 0, stream>>>(Wv, Wqkvb + 8388608, 524288L);
  k_cvt<<<1024, 256, 0, stream>>>(Wo, Wob, 524288L);

  // QKV projection (Q,K normal layout; V transposed)
  k_qkv256<<<3072, 512, 0, stream>>>(xb, Wqkvb, bq, bk, bv, Qb, Kb, Vt);

  // attention, chunked over (b,h) pairs to bound scratch
  for (int base = 0; base < 64; base += NP) {
    int np = (64 - base) < NP ? (64 - base) : NP;
    k_s256<<<np * 10, 512, 0, stream>>>(Qb, Kb, Sc, base);
    k_softmax<<<np * 1024, 256, 0, stream>>>(Sc, Pc);
    k_pv256<<<np * 16, 512, 0, stream>>>(Pc, Vt, Ob, base);
  }

  // output projection
  k_out256<<<1024, 512, 0, stream>>>(Ob, Wob, out);
}

// Round 7
// 1638.127 us; speedup vs baseline: 1.0540x; 1.0540x over previous
//
#include <hip/hip_runtime.h>
#include <hip/hip_bf16.h>
#include <stdint.h>

typedef __bf16 bf16_t;
typedef __bf16 bf16x8 __attribute__((ext_vector_type(8)));
typedef float f32x4 __attribute__((ext_vector_type(4)));
typedef float f32x16 __attribute__((ext_vector_type(16)));

#define AS1(p) ((const __attribute__((address_space(1))) void*)(uintptr_t)(p))
#define AS3(p) ((__attribute__((address_space(3))) void*)(uintptr_t)(p))

__device__ __forceinline__ void gload16(const bf16_t* g, bf16_t* l) {
  __builtin_amdgcn_global_load_lds(AS1(g), AS3(l), 16, 0, 0);
}

#define SB()      __builtin_amdgcn_sched_barrier(0);
#define BAR()     { __builtin_amdgcn_sched_barrier(0); __builtin_amdgcn_s_barrier(); __builtin_amdgcn_sched_barrier(0); }
#define VMCNT0()  { asm volatile("s_waitcnt vmcnt(0)" ::: "memory"); __builtin_amdgcn_sched_barrier(0); }
#define LGKM(n)   { asm volatile("s_waitcnt lgkmcnt(" #n ")" ::: "memory"); __builtin_amdgcn_sched_barrier(0); }

// ========== 256x256 GEMM core (B^T form), 32x32x16 MFMA, pipelined reads ==========
// C[m][n] = sum_k A[m][k]*B[n][k]. 512 threads = 8 waves (2M x 4N), per-wave 128x64.
// BK=64 as 2 k-halves; LDS buf: A kh0|A kh1|B kh0|B kh1 (16KB each); 2 bufs = 128 KiB.
// Half layout [256 rows][32 k] bf16, XOR swizzle byte^=((byte>>7)&7)<<4 (write: linear
// LDS dest + pre-swizzled global source; read: same XOR) -> <=2-way conflicts (free).
// MFMA: 32x32x16 (32/wave/tile, 8.07cy) replaces 16x16x32 (64/wave/tile): -17% pipe
// time, -50% issue slots. A-frag: row=lane&31, k=(lane>>5)*8+j; C/D: col=lane&31,
// row=(reg&3)+8*(reg>>2)+4*(lane>>5) (verified layout, m74/m101).
// Schedule: R3-proven skeleton (stage split across first 2 phases, ONE lgkm0+vmcnt0+
// barrier per tile) + software-pipelined frag reads: phase q issues q+1's reads into
// the alternate reg set, counted lgkmcnt(4/8) drains only the older batch (covered by
// q-1's MFMAs) -> exposed LDS latency 1x/tile instead of 4x. Ledger: 4/8/4/0.
__device__ __forceinline__ void gemm256(const bf16_t* __restrict__ A, int lda,
                                        const bf16_t* __restrict__ B, int ldb,
                                        int nt, f32x16 acc[4][2], bf16_t* lds) {
  const int t = (int)threadIdx.x;
  const int lane = t & 63, w = t >> 6;
  const int wr = w >> 2, wc = w & 3;
  char* ldsb = (char*)lds;

  // staging: thread t writes LDS bytes [t*16,+16) (linear); source pre-swizzled
  const int s0 = (t * 16) ^ (((t >> 3) & 7) << 4);
  const int r0 = s0 >> 6, q0 = (s0 >> 4) & 3;
  const bf16_t* gA0 = A + (size_t)r0 * lda + q0 * 8;
  const bf16_t* gA1 = gA0 + (size_t)128 * lda;
  const bf16_t* gB0 = B + (size_t)r0 * ldb + q0 * 8;
  const bf16_t* gB1 = gB0 + (size_t)128 * ldb;

  // frag read bases (bytes): lane reads row (l&31), k-slice (l>>5)*8 (+ks*16)
  const int row_l = lane & 31, hi = lane >> 5;
  const int y = row_l * 64 + hi * 16;
  const int xo = ((row_l >> 1) & 7) << 4;
  const int yk0 = y ^ xo;
  const int yk1 = (y + 32) ^ xo;
  const int abase = wr * 8192;           // + kh*16384 + rt*2048 + yk{ks}
  const int bbase = 32768 + wc * 4096;   // + kh*16384 + ct*2048 + yk{ks}

  bf16x8 fA[2][4], fB[2][4];  // [set][frag]; A frags: {rt0ks0, rt0ks1, rt1ks0, rt1ks1}

#define STAGE_A(cb, kof) { \
    bf16_t* _d = lds + (cb) * 32768; \
    gload16(gA0 + (kof),      _d + t * 8); \
    gload16(gA1 + (kof),      _d + 4096 + t * 8); \
    gload16(gA0 + (kof) + 32, _d + 8192 + t * 8); \
    gload16(gA1 + (kof) + 32, _d + 12288 + t * 8); \
  } SB()
#define STAGE_B(cb, kof) { \
    bf16_t* _d = lds + (cb) * 32768 + 16384; \
    gload16(gB0 + (kof),      _d + t * 8); \
    gload16(gB1 + (kof),      _d + 4096 + t * 8); \
    gload16(gB0 + (kof) + 32, _d + 8192 + t * 8); \
    gload16(gB1 + (kof) + 32, _d + 12288 + t * 8); \
  } SB()
#define RD(a) (*(const bf16x8*)(ldsb + (a)))
#define READ_B(cb, kh, s) { \
    const int _b = (cb) * 65536 + bbase + (kh) * 16384; \
    fB[s][0] = RD(_b + yk0); fB[s][1] = RD(_b + yk1); \
    fB[s][2] = RD(_b + 2048 + yk0); fB[s][3] = RD(_b + 2048 + yk1); }
#define READ_A(cb, kh, qm, s) { \
    const int _a = (cb) * 65536 + abase + (kh) * 16384 + (qm) * 4096; \
    fA[s][0] = RD(_a + yk0); fA[s][1] = RD(_a + yk1); \
    fA[s][2] = RD(_a + 2048 + yk0); fA[s][3] = RD(_a + 2048 + yk1); }
#define MFMA_P(qm, sa, sb) { \
    __builtin_amdgcn_s_setprio(1); \
    acc[2*(qm)][0]   = __builtin_amdgcn_mfma_f32_32x32x16_bf16(fA[sa][0], fB[sb][0], acc[2*(qm)][0], 0, 0, 0); \
    acc[2*(qm)][1]   = __builtin_amdgcn_mfma_f32_32x32x16_bf16(fA[sa][0], fB[sb][2], acc[2*(qm)][1], 0, 0, 0); \
    acc[2*(qm)+1][0] = __builtin_amdgcn_mfma_f32_32x32x16_bf16(fA[sa][2], fB[sb][0], acc[2*(qm)+1][0], 0, 0, 0); \
    acc[2*(qm)+1][1] = __builtin_amdgcn_mfma_f32_32x32x16_bf16(fA[sa][2], fB[sb][2], acc[2*(qm)+1][1], 0, 0, 0); \
    acc[2*(qm)][0]   = __builtin_amdgcn_mfma_f32_32x32x16_bf16(fA[sa][1], fB[sb][1], acc[2*(qm)][0], 0, 0, 0); \
    acc[2*(qm)][1]   = __builtin_amdgcn_mfma_f32_32x32x16_bf16(fA[sa][1], fB[sb][3], acc[2*(qm)][1], 0, 0, 0); \
    acc[2*(qm)+1][0] = __builtin_amdgcn_mfma_f32_32x32x16_bf16(fA[sa][3], fB[sb][1], acc[2*(qm)+1][0], 0, 0, 0); \
    acc[2*(qm)+1][1] = __builtin_amdgcn_mfma_f32_32x32x16_bf16(fA[sa][3], fB[sb][3], acc[2*(qm)+1][1], 0, 0, 0); \
    __builtin_amdgcn_s_setprio(0); }
#define TILE_BODY(cb) \
    READ_B(cb, 0, 0) READ_A(cb, 0, 0, 0)   /* 8 reads: B kh0 + A kh0 qm0 */ \
    STAGE_A(cb ^ 1, kof)                   /* 4 gloads */ \
    LGKM(0)                                /* tile-top drain (1x exposed latency) */ \
    READ_A(cb, 0, 1, 1)                    /* 4: A kh0 qm1 -> set1 */ \
    STAGE_B(cb ^ 1, kof)                   /* 4 gloads */ \
    MFMA_P(0, 0, 0) \
    READ_B(cb, 1, 1) READ_A(cb, 1, 0, 0)   /* 8: kh1 B + A qm0 */ \
    LGKM(8)                                /* drains A kh0 qm1 */ \
    MFMA_P(1, 1, 0) \
    READ_A(cb, 1, 1, 1)                    /* 4: A kh1 qm1 */ \
    LGKM(4)                                /* drains B kh1 + A kh1 qm0 */ \
    MFMA_P(0, 0, 1) \
    LGKM(0) \
    MFMA_P(1, 1, 1)
#define TILE_TAIL(cb) \
    READ_B(cb, 0, 0) READ_A(cb, 0, 0, 0) \
    LGKM(0) \
    READ_A(cb, 0, 1, 1) \
    MFMA_P(0, 0, 0) \
    READ_B(cb, 1, 1) READ_A(cb, 1, 0, 0) \
    LGKM(8) \
    MFMA_P(1, 1, 0) \
    READ_A(cb, 1, 1, 1) \
    LGKM(4) \
    MFMA_P(0, 0, 1) \
    LGKM(0) \
    MFMA_P(1, 1, 1)

  // prologue: stage tile 0 into buf0, drain, barrier
  STAGE_A(0, 0) STAGE_B(0, 0)
  VMCNT0() BAR()

  int kof = 64;
  for (int tt = 0; tt < nt - 1; ++tt, kof += 64) {
    const int cb = tt & 1;
    TILE_BODY(cb)
    VMCNT0() BAR()   // reads of buf cb drained (LGKM(0) above); writes to cb^1 landed
  }
  { const int cb = (nt - 1) & 1; TILE_TAIL(cb) }
#undef STAGE_A
#undef STAGE_B
#undef RD
#undef READ_B
#undef READ_A
#undef MFMA_P
#undef TILE_BODY
#undef TILE_TAIL
}

#define EPI_VARS \
  const int t = (int)threadIdx.x; \
  const int lane = t & 63, w = t >> 6; \
  const int wr = w >> 2, wc = w & 3; \
  const int colid = lane & 31, hi = lane >> 5;

#define ZERO_ACC(acc) \
  _Pragma("unroll") for (int _i = 0; _i < 4; ++_i) \
  _Pragma("unroll") for (int _j = 0; _j < 2; ++_j) \
  _Pragma("unroll") for (int _k = 0; _k < 16; ++_k) acc[_i][_j][_k] = 0.f;

// C/D 32x32 layout: col = colid, row-in-tile = (i&3) + 8*(i>>2) + 4*hi
#define ROWI(i) (((i) & 3) + (((i) >> 2) << 3) + hi * 4)

// ---------------- conversions ----------------
__global__ void k_cvt(const float* __restrict__ s, bf16_t* __restrict__ d, long n8) {
  long i = (long)blockIdx.x * blockDim.x + threadIdx.x;
  long st = (long)gridDim.x * blockDim.x;
  for (; i < n8; i += st) {
    const float4* sp = (const float4*)(s + i * 8);
    float4 a = sp[0], b = sp[1];
    bf16x8 v;
    v[0] = (__bf16)a.x; v[1] = (__bf16)a.y; v[2] = (__bf16)a.z; v[3] = (__bf16)a.w;
    v[4] = (__bf16)b.x; v[5] = (__bf16)b.y; v[6] = (__bf16)b.z; v[7] = (__bf16)b.w;
    *(bf16x8*)(d + i * 8) = v;
  }
}

__global__ void k_fill(float* o, float v, long n) {
  long i = (long)blockIdx.x * blockDim.x + threadIdx.x;
  long st = (long)gridDim.x * blockDim.x;
  for (; i < n; i += st) o[i] = v;
}

// ---------------- GEMM 1: QKV projection (256-tile) ----------------
__global__ __launch_bounds__(512, 2) void k_qkv256(
    const bf16_t* __restrict__ xb, const bf16_t* __restrict__ Wb,
    const float* __restrict__ bq, const float* __restrict__ bk, const float* __restrict__ bv,
    bf16_t* __restrict__ Q, bf16_t* __restrict__ K, bf16_t* __restrict__ Vt) {
  __shared__ __align__(16) bf16_t lds[65536];
  int bid = (int)blockIdx.x;
  int id = (bid & 7) * 384 + (bid >> 3);  // XCD-bijective swizzle (3072 = 8*384)
  EPI_VARS
  f32x16 acc[4][2];
  ZERO_ACC(acc)

  bool vmode = id >= 2048;
  int mt = 0, ntile = 0, tok = 0, wm = 0;
  const bf16_t *Ap, *Bp;
  if (!vmode) {
    mt = id & 127; ntile = id >> 7;  // B-panel-major: resident blocks share W panel
    Ap = xb + (size_t)mt * 256 * 2048;
    Bp = Wb + (size_t)ntile * 256 * 2048;
  } else {
    int vb = id - 2048;
    tok = vb & 127; wm = vb >> 7;
    Ap = Wb + (size_t)(16 + wm) * 256 * 2048;
    Bp = xb + (size_t)tok * 256 * 2048;
  }
  gemm256(Ap, 2048, Bp, 2048, 32, acc, lds);

  if (!vmode) {
    int sel = ntile >> 3;  // 0 -> Q, 1 -> K
    const float* bias = sel ? bk : bq;
    bf16_t* dst = sel ? K : Q;
    int cbase = (ntile & 7) * 256 + wc * 64 + colid;
#pragma unroll
    for (int ct = 0; ct < 2; ++ct) {
      int c2 = cbase + ct * 32;  // [0,2048)
      int h = c2 >> 10, d = c2 & 1023;
      float bb = bias[c2];
#pragma unroll
      for (int rt = 0; rt < 4; ++rt)
#pragma unroll
        for (int i = 0; i < 16; ++i) {
          int m = mt * 256 + wr * 128 + rt * 32 + ROWI(i);
          int b = m >> 10, tk = m & 1023;
          dst[(((size_t)(b * 2 + h) << 10) + tk) * 1024 + d] = (bf16_t)(acc[rt][ct][i] + bb);
        }
    }
  } else {
#pragma unroll
    for (int rt = 0; rt < 4; ++rt)
#pragma unroll
      for (int i = 0; i < 16; ++i) {
        int gd = wm * 256 + wr * 128 + rt * 32 + ROWI(i);  // [0,2048)
        int h = gd >> 10, dd = gd & 1023;
        float bb = bv[gd];
#pragma unroll
        for (int ct = 0; ct < 2; ++ct) {
          int m = tok * 256 + wc * 64 + ct * 32 + colid;
          int b = m >> 10, tk = m & 1023;
          Vt[(((size_t)(b * 2 + h) << 10) + dd) * 1024 + tk] = (bf16_t)(acc[rt][ct][i] + bb);
        }
      }
  }
}

// ---------------- GEMM 2: S = Q K^T * scale (lower-tri 256-tiles, bf16 out) --------
__global__ __launch_bounds__(512, 2) void k_s256(const bf16_t* __restrict__ Q,
                                                 const bf16_t* __restrict__ K,
                                                 bf16_t* __restrict__ S, int pbase) {
  __shared__ __align__(16) bf16_t lds[65536];
  int id = (int)blockIdx.x;
  int pc = id / 10, rem = id % 10;
  int ti = 0;
  while (rem > ti) { rem -= ti + 1; ++ti; }
  int tj = rem;
  size_t p = (size_t)(pbase + pc);
  EPI_VARS
  f32x16 acc[4][2];
  ZERO_ACC(acc)
  gemm256(Q + (p << 20) + (size_t)ti * 256 * 1024, 1024,
          K + (p << 20) + (size_t)tj * 256 * 1024, 1024, 16, acc, lds);
  bf16_t* Sp = S + ((size_t)pc << 20);
  const float scale = 0.022097086912079608f;  // 1/sqrt(2048)
#pragma unroll
  for (int ct = 0; ct < 2; ++ct) {
    int col = tj * 256 + wc * 64 + ct * 32 + colid;
#pragma unroll
    for (int rt = 0; rt < 4; ++rt)
#pragma unroll
      for (int i = 0; i < 16; ++i) {
        int row = ti * 256 + wr * 128 + rt * 32 + ROWI(i);
        Sp[((size_t)row << 10) + col] = (bf16_t)(acc[rt][ct][i] * scale);
      }
  }
}

// ---------------- softmax (one block per row, causal, bf16 in/out) ----------------
__global__ __launch_bounds__(256) void k_softmax(const bf16_t* __restrict__ S,
                                                 bf16_t* __restrict__ P) {
  int bid = blockIdx.x;
  int pc = bid >> 10, row = bid & 1023;
  const bf16_t* s = S + ((size_t)pc << 20) + ((size_t)row << 10);
  bf16_t* p = P + ((size_t)pc << 20) + ((size_t)row << 10);
  int cend = ((row >> 8) + 1) << 8;  // 256-aligned (PV K-tile width)
  int t = threadIdx.x;
  __shared__ float red[8];
  float x[4];
  float mx = -1e30f;
#pragma unroll
  for (int j = 0; j < 4; ++j) {
    int c = t + 256 * j;
    x[j] = (c <= row) ? (float)s[c] : -1e30f;
    mx = fmaxf(mx, x[j]);
  }
  for (int o = 32; o > 0; o >>= 1) mx = fmaxf(mx, __shfl_xor(mx, o));
  if (!(t & 63)) red[t >> 6] = mx;
  __syncthreads();
  mx = fmaxf(fmaxf(red[0], red[1]), fmaxf(red[2], red[3]));
  float e[4];
  float sum = 0.f;
#pragma unroll
  for (int j = 0; j < 4; ++j) {
    e[j] = (x[j] > -1e29f) ? __expf(x[j] - mx) : 0.f;
    sum += e[j];
  }
  for (int o = 32; o > 0; o >>= 1) sum += __shfl_xor(sum, o);
  if (!(t & 63)) red[4 + (t >> 6)] = sum;
  __syncthreads();
  sum = red[4] + red[5] + red[6] + red[7];
  float inv = 1.f / sum;
#pragma unroll
  for (int j = 0; j < 4; ++j) {
    int c = t + 256 * j;
    if (c < cend) p[c] = (bf16_t)(e[j] * inv);
  }
}

// ---------------- GEMM 3: O = P * V (V pre-transposed; causal-shortened K) ---------
__global__ __launch_bounds__(512, 2) void k_pv256(const bf16_t* __restrict__ P,
                                                  const bf16_t* __restrict__ Vt,
                                                  bf16_t* __restrict__ O, int pbase) {
  __shared__ __align__(16) bf16_t lds[65536];
  int id = (int)blockIdx.x;
  int pc = id >> 4, rem = id & 15;
  int ti = rem >> 2, dj = rem & 3;
  size_t p = (size_t)(pbase + pc);
  EPI_VARS
  f32x16 acc[4][2];
  ZERO_ACC(acc)
  gemm256(P + ((size_t)pc << 20) + (size_t)ti * 256 * 1024, 1024,
          Vt + (p << 20) + (size_t)dj * 256 * 1024, 1024, (ti + 1) * 4, acc, lds);
  int b = (int)(p >> 1), h = (int)(p & 1);
#pragma unroll
  for (int ct = 0; ct < 2; ++ct) {
    int dcol = dj * 256 + wc * 64 + ct * 32 + colid;
#pragma unroll
    for (int rt = 0; rt < 4; ++rt)
#pragma unroll
      for (int i = 0; i < 16; ++i) {
        int tk = ti * 256 + wr * 128 + rt * 32 + ROWI(i);
        O[(((size_t)b << 10) + tk) * 2048 + (h << 10) + dcol] = (bf16_t)acc[rt][ct][i];
      }
  }
}

// ---------------- GEMM 4: out = O * Wo^T (fp32 out) ----------------
__global__ __launch_bounds__(512, 2) void k_out256(const bf16_t* __restrict__ O,
                                                   const bf16_t* __restrict__ W,
                                                   float* __restrict__ out) {
  __shared__ __align__(16) bf16_t lds[65536];
  int bid = (int)blockIdx.x;
  int id = (bid & 7) * 128 + (bid >> 3);  // XCD swizzle (1024 = 8*128)
  int mt = id & 127, ntile = id >> 7;     // B-panel-major
  EPI_VARS
  f32x16 acc[4][2];
  ZERO_ACC(acc)
  gemm256(O + (size_t)mt * 256 * 2048, 2048, W + (size_t)ntile * 256 * 2048, 2048, 32, acc, lds);
#pragma unroll
  for (int ct = 0; ct < 2; ++ct) {
    int col = ntile * 256 + wc * 64 + ct * 32 + colid;
#pragma unroll
    for (int rt = 0; rt < 4; ++rt)
#pragma unroll
      for (int i = 0; i < 16; ++i) {
        int row = mt * 256 + wr * 128 + rt * 32 + ROWI(i);
        out[(size_t)row * 2048 + col] = acc[rt][ct][i];
      }
  }
}

// ---------------- launch ----------------
extern "C" void kernel_launch(void* const* d_in, const int* in_sizes, int n_in,
                              void* d_out, int out_size, void* d_ws, size_t ws_size,
                              hipStream_t stream) {
  const float* x  = (const float*)d_in[0];
  const float* Wq = (const float*)d_in[1];
  const float* bq = (const float*)d_in[2];
  const float* Wk = (const float*)d_in[3];
  const float* bk = (const float*)d_in[4];
  const float* Wv = (const float*)d_in[5];
  const float* bv = (const float*)d_in[6];
  const float* Wo = (const float*)d_in[7];
  float* out = (float*)d_out;

  const size_t MiB = 1ull << 20;
  char* w = (char*)d_ws;
  bf16_t* xb    = (bf16_t*)w;               // 128 MiB, reused as O after QKV
  bf16_t* Ob    = xb;
  bf16_t* Qb    = (bf16_t*)(w + 128 * MiB); // 128 MiB
  bf16_t* Kb    = (bf16_t*)(w + 256 * MiB); // 128 MiB
  bf16_t* Vt    = (bf16_t*)(w + 384 * MiB); // 128 MiB (transposed V)
  bf16_t* Wqkvb = (bf16_t*)(w + 512 * MiB); // 24 MiB  [Wq;Wk;Wv]
  bf16_t* Wob   = (bf16_t*)(w + 536 * MiB); // 8 MiB
  bf16_t* Sc    = (bf16_t*)(w + 544 * MiB); // NP * 2 MiB (bf16 now)

  size_t rem = ws_size > 544 * MiB ? ws_size - 544 * MiB : 0;
  int NP = (int)(rem / (4 * MiB));
  if (NP > 64) NP = 64;
  if (NP < 1) {
    k_fill<<<2048, 256, 0, stream>>>(out, (float)(ws_size >> 20), (long)out_size);
    return;
  }
  bf16_t* Pc = (bf16_t*)(w + 544 * MiB + (size_t)NP * 2 * MiB); // NP * 2 MiB

  // conversions to bf16
  k_cvt<<<2048, 256, 0, stream>>>(x, xb, 8388608L);
  k_cvt<<<1024, 256, 0, stream>>>(Wq, Wqkvb, 524288L);
  k_cvt<<<1024, 256, 0, stream>>>(Wk, Wqkvb + 4194304, 524288L);
  k_cvt<<<1024, 256, 0, stream>>>(Wv, Wqkvb + 8388608, 524288L);
  k_cvt<<<1024, 256, 0, stream>>>(Wo, Wob, 524288L);

  // QKV projection (Q,K normal layout; V transposed)
  k_qkv256<<<3072, 512, 0, stream>>>(xb, Wqkvb, bq, bk, bv, Qb, Kb, Vt);

  // attention, chunked over (b,h) pairs to bound scratch
  for (int base = 0; base < 64; base += NP) {
    int np = (64 - base) < NP ? (64 - base) : NP;
    k_s256<<<np * 10, 512, 0, stream>>>(Qb, Kb, Sc, base);
    k_softmax<<<np * 1024, 256, 0, stream>>>(Sc, Pc);
    k_pv256<<<np * 16, 512, 0, stream>>>(Pc, Vt, Ob, base);
  }

  // output projection
  k_out256<<<1024, 512, 0, stream>>>(Ob, Wob, out);
}

// Round 8
// 1475.182 us; speedup vs baseline: 1.1704x; 1.1105x over previous
//
#include <hip/hip_runtime.h>
#include <hip/hip_bf16.h>
#include <stdint.h>

typedef __bf16 bf16_t;
typedef __bf16 bf16x8 __attribute__((ext_vector_type(8)));
typedef float f32x4 __attribute__((ext_vector_type(4)));

#define AS1(p) ((const __attribute__((address_space(1))) void*)(uintptr_t)(p))
#define AS3(p) ((__attribute__((address_space(3))) void*)(uintptr_t)(p))

__device__ __forceinline__ void gload16(const bf16_t* g, bf16_t* l) {
  __builtin_amdgcn_global_load_lds(AS1(g), AS3(l), 16, 0, 0);
}

#define SB()      __builtin_amdgcn_sched_barrier(0);
#define BAR()     { __builtin_amdgcn_sched_barrier(0); __builtin_amdgcn_s_barrier(); __builtin_amdgcn_sched_barrier(0); }
#define VMCNT(n)  { asm volatile("s_waitcnt vmcnt(" #n ")" ::: "memory"); __builtin_amdgcn_sched_barrier(0); }
#define LGKM(n)   { asm volatile("s_waitcnt lgkmcnt(" #n ")" ::: "memory"); __builtin_amdgcn_sched_barrier(0); }

// ========== 256x256 GEMM core (B^T form), 16x16x32 MFMA, counted-vmcnt 2-window ==========
// C[m][n] = sum_k A[m][k]*B[n][k]. 512 threads = 8 waves (2M x 4N), per-wave 128x64.
// BK=64 as 2 k-halves; LDS buf: A kh0|A kh1|B kh0|B kh1 (16KB each); 2 bufs = 128 KiB.
// Half layout [256 rows][32 k] bf16, XOR swizzle byte^=((byte>>7)&7)<<4 (write: linear
// LDS dest + pre-swizzled global source; read: same XOR) -> 0 bank conflicts (R3-proven).
// Two windows per K-tile (one per k-half). Window:
//   vmcnt(4) -> BAR -> reads(B 4 + A-qm0 4) -> stage A-half(t+1) -> reads(A-qm1 4)
//   -> stage B-half(t+1) -> lgkm(4) -> 16 MFMA -> lgkm(0) -> 16 MFMA
// Ledger (in-order vmcnt): pre-wait outstanding = 8 loads {A0,B0,A1,B1 of tile t};
// winA's vmcnt(4) retires {A0,B0}(t) (issued in winA(t-1)); winB's retires {A1,B1}(t).
// Issue->drain distance = 2 windows (~700cy) hides HBM latency; B panel is L2-hot.
// Cross-wave: per-window barrier after the wait publishes stages; stage regions'
// previous readers drained (lgkm0) before an earlier barrier -> WAR safe.
__device__ __forceinline__ void gemm256(const bf16_t* __restrict__ A, int lda,
                                        const bf16_t* __restrict__ B, int ldb,
                                        int nt, f32x4 acc[8][4], bf16_t* lds) {
  const int t = (int)threadIdx.x;
  const int lane = t & 63, w = t >> 6;
  const int wr = w >> 2, wc = w & 3;
  const int fr = lane & 15, fq = lane >> 4;
  char* ldsb = (char*)lds;

  // staging: thread t writes LDS bytes [t*16,+16) (linear); source pre-swizzled
  const int s0 = (t * 16) ^ (((t >> 3) & 7) << 4);
  const int r0 = s0 >> 6, q0 = (s0 >> 4) & 3;
  const bf16_t* gA0 = A + (size_t)r0 * lda + q0 * 8;
  const bf16_t* gA1 = gA0 + (size_t)128 * lda;
  const bf16_t* gB0 = B + (size_t)r0 * ldb + q0 * 8;
  const bf16_t* gB1 = gB0 + (size_t)128 * ldb;

  // frag read bases (bytes within the 64KB buffer), same XOR (bits[9:7]=fr>>1)
  const int swz = (fr * 64 + fq * 16) ^ (((fr >> 1) & 7) << 4);
  const int abase = wr * 8192 + swz;          // + cb*65536 + kh*16384 + qm*4096
  const int bbase = 32768 + wc * 4096 + swz;  // + cb*65536 + kh*16384

  bf16x8 bb[4], aa0[4], aa1[4];

#define STAGE_A(cb, kh, kof) { \
    bf16_t* _d = lds + (cb) * 32768 + (kh) * 8192; \
    gload16(gA0 + (kof) + (kh) * 32, _d + t * 8); \
    gload16(gA1 + (kof) + (kh) * 32, _d + 4096 + t * 8); \
  } SB()
#define STAGE_B(cb, kh, kof) { \
    bf16_t* _d = lds + (cb) * 32768 + 16384 + (kh) * 8192; \
    gload16(gB0 + (kof) + (kh) * 32, _d + t * 8); \
    gload16(gB1 + (kof) + (kh) * 32, _d + 4096 + t * 8); \
  } SB()
#define READ_B(cb, kh) { \
    const char* _b = ldsb + (cb) * 65536 + (kh) * 16384 + bbase; \
    _Pragma("unroll") for (int n = 0; n < 4; ++n) bb[n] = *(const bf16x8*)(_b + n * 1024); }
#define READ_A(cb, kh, qm, dst) { \
    const char* _a = ldsb + (cb) * 65536 + (kh) * 16384 + abase + (qm) * 4096; \
    _Pragma("unroll") for (int i = 0; i < 4; ++i) dst[i] = *(const bf16x8*)(_a + i * 1024); }
#define MFMA16(dst, qm) { \
    __builtin_amdgcn_s_setprio(1); \
    _Pragma("unroll") for (int i = 0; i < 4; ++i) \
      _Pragma("unroll") for (int n = 0; n < 4; ++n) \
        acc[(qm) * 4 + i][n] = __builtin_amdgcn_mfma_f32_16x16x32_bf16(dst[i], bb[n], acc[(qm) * 4 + i][n], 0, 0, 0); \
    __builtin_amdgcn_s_setprio(0); }

  // prologue: stage tile 0 fully (8 gloads, in ledger order A0,B0,A1,B1)
  STAGE_A(0, 0, 0) STAGE_B(0, 0, 0) STAGE_A(0, 1, 0) STAGE_B(0, 1, 0)

  int kof = 64;
  for (int tt = 0; tt < nt - 1; ++tt, kof += 64) {
    const int cb = tt & 1;
    // window A (k-half 0)
    VMCNT(4) BAR()
    READ_B(cb, 0) READ_A(cb, 0, 0, aa0)
    STAGE_A(cb ^ 1, 0, kof)
    READ_A(cb, 0, 1, aa1)
    STAGE_B(cb ^ 1, 0, kof)
    LGKM(4) MFMA16(aa0, 0)
    LGKM(0) MFMA16(aa1, 1)
    // window B (k-half 1)
    VMCNT(4) BAR()
    READ_B(cb, 1) READ_A(cb, 1, 0, aa0)
    STAGE_A(cb ^ 1, 1, kof)
    READ_A(cb, 1, 1, aa1)
    STAGE_B(cb ^ 1, 1, kof)
    LGKM(4) MFMA16(aa0, 0)
    LGKM(0) MFMA16(aa1, 1)
  }
  {  // tail tile: no staging; drain 4 then 0
    const int cb = (nt - 1) & 1;
    VMCNT(4) BAR()
    READ_B(cb, 0) READ_A(cb, 0, 0, aa0) READ_A(cb, 0, 1, aa1)
    LGKM(4) MFMA16(aa0, 0)
    LGKM(0) MFMA16(aa1, 1)
    VMCNT(0) BAR()
    READ_B(cb, 1) READ_A(cb, 1, 0, aa0) READ_A(cb, 1, 1, aa1)
    LGKM(4) MFMA16(aa0, 0)
    LGKM(0) MFMA16(aa1, 1)
  }
#undef STAGE_A
#undef STAGE_B
#undef READ_B
#undef READ_A
#undef MFMA16
}

#define EPI_VARS \
  const int t = (int)threadIdx.x; \
  const int lane = t & 63, w = t >> 6; \
  const int wr = w >> 2, wc = w & 3; \
  const int fr = lane & 15, fq = lane >> 4;

#define ZERO8x4(acc) \
  _Pragma("unroll") for (int _i = 0; _i < 8; ++_i) \
  _Pragma("unroll") for (int _j = 0; _j < 4; ++_j) { f32x4 _z = {0.f,0.f,0.f,0.f}; acc[_i][_j] = _z; }

// ---------------- conversions ----------------
__global__ void k_cvt(const float* __restrict__ s, bf16_t* __restrict__ d, long n8) {
  long i = (long)blockIdx.x * blockDim.x + threadIdx.x;
  long st = (long)gridDim.x * blockDim.x;
  for (; i < n8; i += st) {
    const float4* sp = (const float4*)(s + i * 8);
    float4 a = sp[0], b = sp[1];
    bf16x8 v;
    v[0] = (__bf16)a.x; v[1] = (__bf16)a.y; v[2] = (__bf16)a.z; v[3] = (__bf16)a.w;
    v[4] = (__bf16)b.x; v[5] = (__bf16)b.y; v[6] = (__bf16)b.z; v[7] = (__bf16)b.w;
    *(bf16x8*)(d + i * 8) = v;
  }
}

__global__ void k_fill(float* o, float v, long n) {
  long i = (long)blockIdx.x * blockDim.x + threadIdx.x;
  long st = (long)gridDim.x * blockDim.x;
  for (; i < n; i += st) o[i] = v;
}

// ---------------- GEMM 1: QKV projection (256-tile) ----------------
__global__ __launch_bounds__(512, 2) void k_qkv256(
    const bf16_t* __restrict__ xb, const bf16_t* __restrict__ Wb,
    const float* __restrict__ bq, const float* __restrict__ bk, const float* __restrict__ bv,
    bf16_t* __restrict__ Q, bf16_t* __restrict__ K, bf16_t* __restrict__ Vt) {
  __shared__ __align__(16) bf16_t lds[65536];
  int bid = (int)blockIdx.x;
  int id = (bid & 7) * 384 + (bid >> 3);  // XCD-bijective swizzle (3072 = 8*384)
  EPI_VARS
  f32x4 acc[8][4];
  ZERO8x4(acc)

  bool vmode = id >= 2048;
  int mt = 0, ntile = 0, tok = 0, wm = 0;
  const bf16_t *Ap, *Bp;
  if (!vmode) {
    mt = id & 127; ntile = id >> 7;  // B-panel-major: resident blocks share W panel
    Ap = xb + (size_t)mt * 256 * 2048;
    Bp = Wb + (size_t)ntile * 256 * 2048;
  } else {
    int vb = id - 2048;
    tok = vb & 127; wm = vb >> 7;
    Ap = Wb + (size_t)(16 + wm) * 256 * 2048;
    Bp = xb + (size_t)tok * 256 * 2048;
  }
  gemm256(Ap, 2048, Bp, 2048, 32, acc, lds);

  if (!vmode) {
    int sel = ntile >> 3;  // 0 -> Q, 1 -> K
    const float* bias = sel ? bk : bq;
    bf16_t* dst = sel ? K : Q;
    int cbase = (ntile & 7) * 256 + wc * 64;
#pragma unroll
    for (int ni = 0; ni < 4; ++ni) {
      int c2 = cbase + ni * 16 + fr;  // [0,2048)
      int h = c2 >> 10, d = c2 & 1023;
      float bb = bias[c2];
#pragma unroll
      for (int mi = 0; mi < 8; ++mi) {
        f32x4 a = acc[mi][ni];
#pragma unroll
        for (int r = 0; r < 4; ++r) {
          int m = mt * 256 + wr * 128 + mi * 16 + fq * 4 + r;
          int b = m >> 10, tk = m & 1023;
          dst[(((size_t)(b * 2 + h) << 10) + tk) * 1024 + d] = (bf16_t)(a[r] + bb);
        }
      }
    }
  } else {
#pragma unroll
    for (int mi = 0; mi < 8; ++mi) {
#pragma unroll
      for (int r = 0; r < 4; ++r) {
        int gd = wm * 256 + wr * 128 + mi * 16 + fq * 4 + r;  // [0,2048)
        int h = gd >> 10, dd = gd & 1023;
        float bb = bv[gd];
#pragma unroll
        for (int ni = 0; ni < 4; ++ni) {
          int m = tok * 256 + wc * 64 + ni * 16 + fr;
          int b = m >> 10, tk = m & 1023;
          Vt[(((size_t)(b * 2 + h) << 10) + dd) * 1024 + tk] = (bf16_t)(acc[mi][ni][r] + bb);
        }
      }
    }
  }
}

// ---------------- GEMM 2: S = Q K^T * scale (lower-tri 256-tiles, bf16 out) --------
__global__ __launch_bounds__(512, 2) void k_s256(const bf16_t* __restrict__ Q,
                                                 const bf16_t* __restrict__ K,
                                                 bf16_t* __restrict__ S, int pbase) {
  __shared__ __align__(16) bf16_t lds[65536];
  int id = (int)blockIdx.x;
  int pc = id / 10, rem = id % 10;
  int ti = 0;
  while (rem > ti) { rem -= ti + 1; ++ti; }
  int tj = rem;
  size_t p = (size_t)(pbase + pc);
  EPI_VARS
  f32x4 acc[8][4];
  ZERO8x4(acc)
  gemm256(Q + (p << 20) + (size_t)ti * 256 * 1024, 1024,
          K + (p << 20) + (size_t)tj * 256 * 1024, 1024, 16, acc, lds);
  bf16_t* Sp = S + ((size_t)pc << 20);
  const float scale = 0.022097086912079608f;  // 1/sqrt(2048)
#pragma unroll
  for (int mi = 0; mi < 8; ++mi)
#pragma unroll
    for (int ni = 0; ni < 4; ++ni) {
      int col = tj * 256 + wc * 64 + ni * 16 + fr;
      f32x4 a = acc[mi][ni];
#pragma unroll
      for (int r = 0; r < 4; ++r) {
        int row = ti * 256 + wr * 128 + mi * 16 + fq * 4 + r;
        Sp[((size_t)row << 10) + col] = (bf16_t)(a[r] * scale);
      }
    }
}

// ------- softmax: one ROW per wave (4 rows/block), vectorized bf16x8, causal -------
__global__ __launch_bounds__(256) void k_softmax(const bf16_t* __restrict__ S,
                                                 bf16_t* __restrict__ P) {
  int gw = (int)blockIdx.x * 4 + ((int)threadIdx.x >> 6);
  int pc = gw >> 10, row = gw & 1023;
  int lane = (int)threadIdx.x & 63;
  const bf16_t* s = S + ((size_t)pc << 20) + ((size_t)row << 10);
  bf16_t* p = P + ((size_t)pc << 20) + ((size_t)row << 10);
  int cend = ((row >> 8) + 1) << 8;  // 256-aligned (PV K-tile width)
  bf16x8 v0 = *(const bf16x8*)(s + lane * 8);
  bf16x8 v1 = *(const bf16x8*)(s + 512 + lane * 8);
  float x[16];
  float mx = -1e30f;
#pragma unroll
  for (int j = 0; j < 8; ++j) {
    int c0 = lane * 8 + j, c1 = 512 + lane * 8 + j;
    x[j]     = (c0 <= row) ? (float)v0[j] : -1e30f;
    x[8 + j] = (c1 <= row) ? (float)v1[j] : -1e30f;
    mx = fmaxf(mx, fmaxf(x[j], x[8 + j]));
  }
  for (int o = 32; o > 0; o >>= 1) mx = fmaxf(mx, __shfl_xor(mx, o));
  float sum = 0.f;
#pragma unroll
  for (int j = 0; j < 16; ++j) {
    x[j] = (x[j] > -1e29f) ? __expf(x[j] - mx) : 0.f;
    sum += x[j];
  }
  for (int o = 32; o > 0; o >>= 1) sum += __shfl_xor(sum, o);
  float inv = 1.f / sum;
  bf16x8 o0, o1;
#pragma unroll
  for (int j = 0; j < 8; ++j) {
    o0[j] = (bf16_t)(x[j] * inv);
    o1[j] = (bf16_t)(x[8 + j] * inv);
  }
  if (lane * 8 < cend)       *(bf16x8*)(p + lane * 8) = o0;
  if (512 + lane * 8 < cend) *(bf16x8*)(p + 512 + lane * 8) = o1;
}

// ---------------- GEMM 3: O = P * V (V pre-transposed; causal-shortened K) ---------
__global__ __launch_bounds__(512, 2) void k_pv256(const bf16_t* __restrict__ P,
                                                  const bf16_t* __restrict__ Vt,
                                                  bf16_t* __restrict__ O, int pbase) {
  __shared__ __align__(16) bf16_t lds[65536];
  int id = (int)blockIdx.x;
  int pc = id >> 4, rem = id & 15;
  int ti = rem >> 2, dj = rem & 3;
  size_t p = (size_t)(pbase + pc);
  EPI_VARS
  f32x4 acc[8][4];
  ZERO8x4(acc)
  gemm256(P + ((size_t)pc << 20) + (size_t)ti * 256 * 1024, 1024,
          Vt + (p << 20) + (size_t)dj * 256 * 1024, 1024, (ti + 1) * 4, acc, lds);
  int b = (int)(p >> 1), h = (int)(p & 1);
#pragma unroll
  for (int mi = 0; mi < 8; ++mi)
#pragma unroll
    for (int ni = 0; ni < 4; ++ni) {
      int dcol = dj * 256 + wc * 64 + ni * 16 + fr;
      f32x4 a = acc[mi][ni];
#pragma unroll
      for (int r = 0; r < 4; ++r) {
        int tk = ti * 256 + wr * 128 + mi * 16 + fq * 4 + r;
        O[(((size_t)b << 10) + tk) * 2048 + (h << 10) + dcol] = (bf16_t)a[r];
      }
    }
}

// ---------------- GEMM 4: out = O * Wo^T (fp32 out) ----------------
__global__ __launch_bounds__(512, 2) void k_out256(const bf16_t* __restrict__ O,
                                                   const bf16_t* __restrict__ W,
                                                   float* __restrict__ out) {
  __shared__ __align__(16) bf16_t lds[65536];
  int bid = (int)blockIdx.x;
  int id = (bid & 7) * 128 + (bid >> 3);  // XCD swizzle (1024 = 8*128)
  int mt = id & 127, ntile = id >> 7;     // B-panel-major
  EPI_VARS
  f32x4 acc[8][4];
  ZERO8x4(acc)
  gemm256(O + (size_t)mt * 256 * 2048, 2048, W + (size_t)ntile * 256 * 2048, 2048, 32, acc, lds);
#pragma unroll
  for (int mi = 0; mi < 8; ++mi)
#pragma unroll
    for (int ni = 0; ni < 4; ++ni) {
      int col = ntile * 256 + wc * 64 + ni * 16 + fr;
      f32x4 a = acc[mi][ni];
#pragma unroll
      for (int r = 0; r < 4; ++r) {
        int row = mt * 256 + wr * 128 + mi * 16 + fq * 4 + r;
        out[(size_t)row * 2048 + col] = a[r];
      }
    }
}

// ---------------- launch ----------------
extern "C" void kernel_launch(void* const* d_in, const int* in_sizes, int n_in,
                              void* d_out, int out_size, void* d_ws, size_t ws_size,
                              hipStream_t stream) {
  const float* x  = (const float*)d_in[0];
  const float* Wq = (const float*)d_in[1];
  const float* bq = (const float*)d_in[2];
  const float* Wk = (const float*)d_in[3];
  const float* bk = (const float*)d_in[4];
  const float* Wv = (const float*)d_in[5];
  const float* bv = (const float*)d_in[6];
  const float* Wo = (const float*)d_in[7];
  float* out = (float*)d_out;

  const size_t MiB = 1ull << 20;
  char* w = (char*)d_ws;
  bf16_t* xb    = (bf16_t*)w;               // 128 MiB, reused as O after QKV
  bf16_t* Ob    = xb;
  bf16_t* Qb    = (bf16_t*)(w + 128 * MiB); // 128 MiB
  bf16_t* Kb    = (bf16_t*)(w + 256 * MiB); // 128 MiB
  bf16_t* Vt    = (bf16_t*)(w + 384 * MiB); // 128 MiB (transposed V)
  bf16_t* Wqkvb = (bf16_t*)(w + 512 * MiB); // 24 MiB  [Wq;Wk;Wv]
  bf16_t* Wob   = (bf16_t*)(w + 536 * MiB); // 8 MiB
  bf16_t* Sc    = (bf16_t*)(w + 544 * MiB); // NP * 2 MiB (bf16)

  size_t rem = ws_size > 544 * MiB ? ws_size - 544 * MiB : 0;
  int NP = (int)(rem / (4 * MiB));
  if (NP > 64) NP = 64;
  if (NP < 1) {
    k_fill<<<2048, 256, 0, stream>>>(out, (float)(ws_size >> 20), (long)out_size);
    return;
  }
  bf16_t* Pc = (bf16_t*)(w + 544 * MiB + (size_t)NP * 2 * MiB); // NP * 2 MiB

  // conversions to bf16
  k_cvt<<<2048, 256, 0, stream>>>(x, xb, 8388608L);
  k_cvt<<<1024, 256, 0, stream>>>(Wq, Wqkvb, 524288L);
  k_cvt<<<1024, 256, 0, stream>>>(Wk, Wqkvb + 4194304, 524288L);
  k_cvt<<<1024, 256, 0, stream>>>(Wv, Wqkvb + 8388608, 524288L);
  k_cvt<<<1024, 256, 0, stream>>>(Wo, Wob, 524288L);

  // QKV projection (Q,K normal layout; V transposed)
  k_qkv256<<<3072, 512, 0, stream>>>(xb, Wqkvb, bq, bk, bv, Qb, Kb, Vt);

  // attention, chunked over (b,h) pairs to bound scratch
  for (int base = 0; base < 64; base += NP) {
    int np = (64 - base) < NP ? (64 - base) : NP;
    k_s256<<<np * 10, 512, 0, stream>>>(Qb, Kb, Sc, base);
    k_softmax<<<np * 256, 256, 0, stream>>>(Sc, Pc);
    k_pv256<<<np * 16, 512, 0, stream>>>(Pc, Vt, Ob, base);
  }

  // output projection
  k_out256<<<1024, 512, 0, stream>>>(Ob, Wob, out);
}